// Round 4
// baseline (90.498 us; speedup 1.0000x reference)
//
#include <hip/hip_runtime.h>

#define NPTS   8192
#define BLOCK  256
#define SPLIT  32                 // j-dimension split for parallelism
#define JTILE  (NPTS / SPLIT)     // 256 j's staged per block

// out layout: [0 .. 3N)  = -dH/dq   (output 0)
//             [3N .. 6N) =  dH/dp   (output 1)
__global__ __launch_bounds__(BLOCK) void lddmm_hamilton_kernel(
    const float* __restrict__ mom,  // [N,3]  d_in[0]
    const float* __restrict__ q,    // [N,3]  d_in[1]
    float* __restrict__ out)        // [2,N,3]
{
    __shared__ float4 sq[JTILE];    // (qx, qy, qz, px)
    __shared__ float2 sp[JTILE];    // (py, pz)

    const int ib = blockIdx.x & (NPTS / BLOCK - 1);   // 0..31  i-chunk
    const int js = blockIdx.x >> 5;                   // 0..SPLIT-1  j-chunk
    const int i  = ib * BLOCK + threadIdx.x;
    const int j0 = js * JTILE;

    // cooperative stage of the j tile into LDS (1 j per thread since JTILE==BLOCK)
    {
        const int j = j0 + threadIdx.x;
        const float qx = q[3 * j], qy = q[3 * j + 1], qz = q[3 * j + 2];
        const float px = mom[3 * j], py = mom[3 * j + 1], pz = mom[3 * j + 2];
        sq[threadIdx.x] = make_float4(qx, qy, qz, px);
        sp[threadIdx.x] = make_float2(py, pz);
    }
    __syncthreads();

    const float qix = q[3 * i], qiy = q[3 * i + 1], qiz = q[3 * i + 2];
    const float pix = mom[3 * i], piy = mom[3 * i + 1], piz = mom[3 * i + 2];

    float a0 = 0.f, a1 = 0.f, a2 = 0.f;   // Σ K (pi·pj) (qi - qj)
    float m0 = 0.f, m1 = 0.f, m2 = 0.f;   // Σ K pj

    #pragma unroll 8
    for (int t = 0; t < JTILE; ++t) {
        const float4 a = sq[t];           // broadcast ds_read_b128
        const float2 b = sp[t];           // broadcast ds_read_b64
        const float dx = qix - a.x;
        const float dy = qiy - a.y;
        const float dz = qiz - a.z;
        const float d2 = dx * dx + dy * dy + dz * dz;
        const float K  = __expf(-100.0f * d2);       // v_mul + v_exp_f32
        const float dot = pix * a.w + piy * b.x + piz * b.y;
        m0 += K * a.w;
        m1 += K * b.x;
        m2 += K * b.y;
        const float w = K * dot;
        a0 += w * dx;
        a1 += w * dy;
        a2 += w * dz;
    }

    // output 0: -dH/dq = +400 * Σ K (pi·pj)(qi-qj)
    atomicAdd(&out[3 * i + 0], 400.0f * a0);
    atomicAdd(&out[3 * i + 1], 400.0f * a1);
    atomicAdd(&out[3 * i + 2], 400.0f * a2);
    // output 1: dH/dp = 2 * Σ K pj
    atomicAdd(&out[3 * NPTS + 3 * i + 0], 2.0f * m0);
    atomicAdd(&out[3 * NPTS + 3 * i + 1], 2.0f * m1);
    atomicAdd(&out[3 * NPTS + 3 * i + 2], 2.0f * m2);
}

extern "C" void kernel_launch(void* const* d_in, const int* in_sizes, int n_in,
                              void* d_out, int out_size, void* d_ws, size_t ws_size,
                              hipStream_t stream) {
    const float* mom = (const float*)d_in[0];   // setup_inputs order: mom first
    const float* q   = (const float*)d_in[1];   // then control_points
    float* out = (float*)d_out;

    // d_out is poisoned with 0xAA before every timed launch; we accumulate with
    // atomics, so zero it first (async memset is graph-capture safe).
    hipMemsetAsync(out, 0, (size_t)out_size * sizeof(float), stream);

    const dim3 grid(SPLIT * (NPTS / BLOCK));    // 1024 blocks
    lddmm_hamilton_kernel<<<grid, BLOCK, 0, stream>>>(mom, q, out);
}

// Round 5
// 79.797 us; speedup vs baseline: 1.1341x; 1.1341x over previous
//
#include <hip/hip_runtime.h>

#define NPTS   8192
#define BLOCK  256
#define IB     64                  // i's per block
#define NSUB   4                   // j-subsplits per block (one per wave)
#define JS     16                  // grid-level j splits
#define JTILE  128                 // j's per thread = NPTS/(NSUB*JS)
#define JBLK   (NSUB*JTILE)        // 512 j's staged per block
#define NPAIR  (JBLK/2)            // 256 packed pairs per component array

typedef float v2f __attribute__((ext_vector_type(2)));

#if __has_builtin(__builtin_amdgcn_exp2f)
#define EXP2(x) __builtin_amdgcn_exp2f(x)
#else
#define EXP2(x) exp2f(x)
#endif

// K = exp(-100*d2) = exp2(-100*log2(e)*d2)
#define NEG100_LOG2E  (-144.26950408889634f)

// out: [0..3N) = -dH/dq = +400*sum_j K*(pi.pj)*(qi-qj); [3N..6N) = dH/dp = 2*sum_j K*pj
__global__ __launch_bounds__(BLOCK, 8) void lddmm_hamilton_kernel(
    const float* __restrict__ mom,  // [N,3]
    const float* __restrict__ q,    // [N,3]
    float* __restrict__ out)        // [2,N,3]
{
    // Packed j-tile, pair layout (one ds_read_b128 = two j's of two components):
    //   sT[0   ..255] A = (qx0,qx1, qy0,qy1)
    //   sT[256 ..511] B = (qz0,qz1, px0,px1)
    //   sT[512 ..767] C = (py0,py1, pz0,pz1)
    // After the loop this buffer is re-aliased as float partial[NSUB][IB][6].
    __shared__ float4 sT[3 * NPAIR];

    const int tid  = threadIdx.x;
    const int ib   = blockIdx.x & (NPTS/IB - 1);   // 0..127
    const int jsg  = blockIdx.x >> 7;              // 0..15
    const int iloc = tid & 63;
    const int jsub = tid >> 6;                     // 0..3 == wave id
    const int i    = ib * IB + iloc;
    const int j0   = jsg * JBLK;

    // stage: thread tid packs j-pair (j0+2tid, j0+2tid+1)
    {
        const int j = j0 + 2 * tid;
        const float* qa = q   + 3 * j;   // qx0 qy0 qz0 qx1 qy1 qz1
        const float* pa = mom + 3 * j;
        sT[tid]             = make_float4(qa[0], qa[3], qa[1], qa[4]);
        sT[NPAIR   + tid]   = make_float4(qa[2], qa[5], pa[0], pa[3]);
        sT[2*NPAIR + tid]   = make_float4(pa[1], pa[4], pa[2], pa[5]);
    }

    // per-i values (coalesced: consecutive lanes -> consecutive i)
    const float qix = q[3*i], qiy = q[3*i+1], qiz = q[3*i+2];
    const float pix = mom[3*i], piy = mom[3*i+1], piz = mom[3*i+2];

    __syncthreads();

    const float4* tA = sT             + jsub * (JTILE/2);
    const float4* tB = sT + NPAIR     + jsub * (JTILE/2);
    const float4* tC = sT + 2*NPAIR   + jsub * (JTILE/2);

    v2f a0 = {0.f,0.f}, a1 = {0.f,0.f}, a2 = {0.f,0.f};
    v2f m0 = {0.f,0.f}, m1 = {0.f,0.f}, m2 = {0.f,0.f};

    #pragma unroll 2
    for (int t = 0; t < JTILE/2; ++t) {
        const float4 A = tA[t];          // wave-uniform broadcast ds_read_b128
        const float4 B = tB[t];
        const float4 C = tC[t];
        const v2f qx = {A.x, A.y}, qy = {A.z, A.w};
        const v2f qz = {B.x, B.y}, px = {B.z, B.w};
        const v2f py = {C.x, C.y}, pz = {C.z, C.w};

        const v2f dx = qix - qx;
        const v2f dy = qiy - qy;
        const v2f dz = qiz - qz;
        const v2f d2 = dx*dx + dy*dy + dz*dz;
        const v2f arg = d2 * NEG100_LOG2E;
        v2f K; K.x = EXP2(arg.x); K.y = EXP2(arg.y);
        const v2f dot = pix*px + piy*py + piz*pz;
        m0 += K * px;  m1 += K * py;  m2 += K * pz;
        const v2f w = K * dot;
        a0 += w * dx;  a1 += w * dy;  a2 += w * dz;
    }

    // horizontal add of packed halves
    float r[6] = { a0.x + a0.y, a1.x + a1.y, a2.x + a2.y,
                   m0.x + m0.y, m1.x + m1.y, m2.x + m2.y };

    __syncthreads();                      // everyone done reading the tile
    float* pr = (float*)sT;               // alias: partial[NSUB][IB][6] (1536 floats <= 3072)
    #pragma unroll
    for (int c = 0; c < 6; ++c) pr[(jsub*IB + iloc)*6 + c] = r[c];
    __syncthreads();

    // cross-wave reduce + one atomic per (i, component) per block
    #pragma unroll
    for (int pass = 0; pass < 2; ++pass) {
        const int t  = tid + pass * BLOCK;    // 0..511
        const int il = t >> 3;                // 0..63
        const int c  = t & 7;                 // 0..7 (c>=6 idle)
        if (c < 6) {
            float s = 0.f;
            #pragma unroll
            for (int js2 = 0; js2 < NSUB; ++js2) s += pr[(js2*IB + il)*6 + c];
            const int ii = ib * IB + il;
            if (c < 3) atomicAdd(&out[3*ii + c],             400.0f * s);
            else       atomicAdd(&out[3*NPTS + 3*ii + (c-3)],  2.0f * s);
        }
    }
}

extern "C" void kernel_launch(void* const* d_in, const int* in_sizes, int n_in,
                              void* d_out, int out_size, void* d_ws, size_t ws_size,
                              hipStream_t stream) {
    const float* mom = (const float*)d_in[0];   // setup_inputs order: mom first
    const float* q   = (const float*)d_in[1];   // then control_points
    float* out = (float*)d_out;

    // d_out is re-poisoned to 0xAA before every timed launch; atomics need zeros.
    hipMemsetAsync(out, 0, (size_t)out_size * sizeof(float), stream);

    const dim3 grid((NPTS/IB) * JS);            // 128 * 16 = 2048 blocks = 32 waves/CU
    lddmm_hamilton_kernel<<<grid, BLOCK, 0, stream>>>(mom, q, out);
}